// Round 7
// baseline (19.359 us; speedup 1.0000x reference)
//
#include <hip/hip_runtime.h>

#define HWD    48400          // 220*220
#define PATCHD 75
#define NPOS   96800          // 2 * HWD
#define KPAD   96             // padded K per half (3 MFMA K-steps of 32)

typedef __attribute__((ext_vector_type(8))) _Float16 f16x8;
typedef __attribute__((ext_vector_type(2))) __fp16   h16x2;   // cvt_pkrtz return type
typedef __attribute__((ext_vector_type(4))) float    f32x4;

union U2 { h16x2 h; unsigned u; };
union UF { unsigned u[4]; f16x8 v; };

#define GLOAD_LDS16(g, l) __builtin_amdgcn_global_load_lds(               \
    (const __attribute__((address_space(1))) void*)(g),                   \
    (__attribute__((address_space(3))) void*)(l), 16, 0, 0)

// ---------------------------------------------------------------------------
// Table build (unchanged): tbl[role][c][k], f16, k-major, zero-padded to KPAD.
//   role 0 = exp(k1), 1 = k1*exp(k1), 2 = exp(k2), 3 = k2*exp(k2)
// ---------------------------------------------------------------------------
__global__ void smorph_build_tables(const float* __restrict__ k1,
                                    const float* __restrict__ k2,
                                    _Float16* __restrict__ tbl)
{
    int i = (int)blockIdx.x * 256 + (int)threadIdx.x;   // (dir, c, k)
    if (i >= 2 * 16 * KPAD) return;
    int dir = i / (16 * KPAD);
    int r   = i - dir * (16 * KPAD);
    int c   = r / KPAD;
    int k   = r - c * KPAD;
    const float* kw = dir ? k2 : k1;
    float a = 0.f, b = 0.f;
    if (k < PATCHD) {
        float w = kw[k * 16 + c];
        float e = __expf(w);
        a = e;
        b = w * e;
    }
    tbl[(dir * 2 + 0) * (16 * KPAD) + c * KPAD + k] = (_Float16)a;
    tbl[(dir * 2 + 1) * (16 * KPAD) + c * KPAD + k] = (_Float16)b;
}

// ---------------------------------------------------------------------------
// Main: 64 positions/block (4 waves x 16), x staged via global_load_lds into
// double-buffered LDS [32 k][64 pos]; weight fragments live in registers.
// ---------------------------------------------------------------------------
__global__ __launch_bounds__(256, 4)
void smorph_mfma4(const float* __restrict__ x,
                  const _Float16* __restrict__ tbl,
                  const float* __restrict__ bias,
                  float* __restrict__ out)
{
    __shared__ __align__(16) float sX[2][32][64];    // 16 KB double buffer

    const int tid = (int)threadIdx.x;
    const int l   = tid & 63;
    const int w   = tid >> 6;
    const int g   = l >> 4;         // k-subgroup 0..3
    const int c   = l & 15;         // channel lane (A) / position lane (B,D)

    int p0_blk = (int)blockIdx.x * 64;
    if (p0_blk > NPOS - 64) p0_blk = NPOS - 64;      // full block, dup stores OK

    // ---- staging geometry: lane l covers row (2w+i)*4+g, positions 4c..4c+3
    const int ps   = p0_blk + 4 * c;                 // chunk base (chunk-aligned vs HWD)
    const int sb   = (ps >= HWD) ? 1 : 0;            // per-lane batch
    const float* sg = x + (size_t)sb * PATCHD * HWD + (ps - sb * HWD);

    #define STAGE(buf, s)                                                     \
        {                                                                     \
            _Pragma("unroll")                                                 \
            for (int i = 0; i < 2; ++i) {                                     \
                const int row = (2 * w + i) * 4 + g;                          \
                const int k   = 32 * (s) + row;                               \
                if (k < PATCHD)                                               \
                    GLOAD_LDS16(sg + (size_t)k * HWD, &sX[buf][(2 * w + i) * 4][0]); \
            }                                                                 \
        }

    // ---- wave compute geometry ----
    const int pcol = w * 16 + c;                     // LDS position column
    const int p0w  = p0_blk + w * 16;
    const int b    = (p0w >= HWD) ? 1 : 0;           // HWD % 16 == 0: no straddle
    const int hw0  = p0w - b * HWD;

    // ---- weight fragments: 48 dwords, loop-invariant, L1-resident ----
    UF Ta1[3], Tb1[3], Ta2[3], Tb2[3];
    const _Float16* t0 = tbl + c * KPAD;
    #pragma unroll
    for (int s = 0; s < 3; ++s)
        #pragma unroll
        for (int jp = 0; jp < 4; ++jp) {
            const int off = 32 * s + 8 * g + 2 * jp;
            Ta1[s].u[jp] = *(const unsigned*)(t0 + 0 * 16 * KPAD + off);
            Tb1[s].u[jp] = *(const unsigned*)(t0 + 1 * 16 * KPAD + off);
            Ta2[s].u[jp] = *(const unsigned*)(t0 + 2 * 16 * KPAD + off);
            Tb2[s].u[jp] = *(const unsigned*)(t0 + 3 * 16 * KPAD + off);
        }

    f32x4 aN1 = {0.f,0.f,0.f,0.f}, aD1 = {0.f,0.f,0.f,0.f};
    f32x4 aN2 = {0.f,0.f,0.f,0.f}, aD2 = {0.f,0.f,0.f,0.f};

    #define COMPUTE(buf, s)                                                   \
        {                                                                     \
            const float* lp = &sX[buf][8 * g][pcol];                          \
            float xv[8];                                                      \
            _Pragma("unroll")                                                 \
            for (int j = 0; j < 8; ++j) xv[j] = lp[j * 64];                   \
            _Pragma("unroll")                                                 \
            for (int j = 0; j < 8; ++j)                                       \
                if (32 * (s) + 8 * g + j >= PATCHD) xv[j] = 0.f;              \
            float E[8], R[8];                                                 \
            _Pragma("unroll")                                                 \
            for (int j = 0; j < 8; ++j) { E[j] = __expf(xv[j]); R[j] = __expf(-xv[j]); } \
            UF fEx, fE, fRx, fR;                                              \
            _Pragma("unroll")                                                 \
            for (int jp = 0; jp < 4; ++jp) {                                  \
                U2 q;                                                         \
                q.h = __builtin_amdgcn_cvt_pkrtz(E[2*jp] * xv[2*jp], E[2*jp+1] * xv[2*jp+1]);   \
                fEx.u[jp] = q.u;                                              \
                q.h = __builtin_amdgcn_cvt_pkrtz(E[2*jp], E[2*jp+1]);         \
                fE.u[jp]  = q.u;                                              \
                q.h = __builtin_amdgcn_cvt_pkrtz(-R[2*jp] * xv[2*jp], -R[2*jp+1] * xv[2*jp+1]); \
                fRx.u[jp] = q.u;                                              \
                q.h = __builtin_amdgcn_cvt_pkrtz(R[2*jp], R[2*jp+1]);         \
                fR.u[jp]  = q.u;                                              \
            }                                                                 \
            aN1 = __builtin_amdgcn_mfma_f32_16x16x32_f16(Ta1[s].v, fEx.v, aN1, 0, 0, 0); \
            aN1 = __builtin_amdgcn_mfma_f32_16x16x32_f16(Tb1[s].v, fE.v,  aN1, 0, 0, 0); \
            aD1 = __builtin_amdgcn_mfma_f32_16x16x32_f16(Ta1[s].v, fE.v,  aD1, 0, 0, 0); \
            aN2 = __builtin_amdgcn_mfma_f32_16x16x32_f16(Ta2[s].v, fRx.v, aN2, 0, 0, 0); \
            aN2 = __builtin_amdgcn_mfma_f32_16x16x32_f16(Tb2[s].v, fR.v,  aN2, 0, 0, 0); \
            aD2 = __builtin_amdgcn_mfma_f32_16x16x32_f16(Ta2[s].v, fR.v,  aD2, 0, 0, 0); \
        }

    // ---- 3-step double-buffered pipeline (all waves hit all barriers) ----
    STAGE(0, 0);
    __syncthreads();                 // drains stage(0,0)
    STAGE(1, 1);                     // prefetch s=1 under compute s=0
    COMPUTE(0, 0);
    __syncthreads();                 // drains stage(1,1); buf0 free
    STAGE(0, 2);                     // prefetch s=2 under compute s=1
    COMPUTE(1, 1);
    __syncthreads();                 // drains stage(0,2)
    COMPUTE(0, 2);

    // ---- epilogue ----
    const float4 bsv = *(const float4*)(bias + 4 * g);
    float* ob = out + ((size_t)(b * 16 + 4 * g)) * HWD + hw0 + c;
    {
        const float y0 = aN1[0] * __builtin_amdgcn_rcpf(aD1[0]) + aN2[0] * __builtin_amdgcn_rcpf(aD2[0]) + bsv.x;
        const float y1 = aN1[1] * __builtin_amdgcn_rcpf(aD1[1]) + aN2[1] * __builtin_amdgcn_rcpf(aD2[1]) + bsv.y;
        const float y2 = aN1[2] * __builtin_amdgcn_rcpf(aD1[2]) + aN2[2] * __builtin_amdgcn_rcpf(aD2[2]) + bsv.z;
        const float y3 = aN1[3] * __builtin_amdgcn_rcpf(aD1[3]) + aN2[3] * __builtin_amdgcn_rcpf(aD2[3]) + bsv.w;
        ob[0 * (size_t)HWD] = y0;
        ob[1 * (size_t)HWD] = y1;
        ob[2 * (size_t)HWD] = y2;
        ob[3 * (size_t)HWD] = y3;
    }
}

extern "C" void kernel_launch(void* const* d_in, const int* in_sizes, int n_in,
                              void* d_out, int out_size, void* d_ws, size_t ws_size,
                              hipStream_t stream)
{
    const float* x    = (const float*)d_in[0];
    const float* k1   = (const float*)d_in[1];
    const float* k2   = (const float*)d_in[2];
    const float* bias = (const float*)d_in[3];
    float* out = (float*)d_out;
    _Float16* tbl = (_Float16*)d_ws;     // 12 KB

    smorph_build_tables<<<(2 * 16 * KPAD + 255) / 256, 256, 0, stream>>>(k1, k2, tbl);
    smorph_mfma4<<<(NPOS + 63) / 64, 256, 0, stream>>>(x, tbl, bias, out);
}

// Round 8
// 18.833 us; speedup vs baseline: 1.0279x; 1.0279x over previous
//
#include <hip/hip_runtime.h>

#define HWD    48400          // 220*220
#define PATCHD 75
#define NPOS   96800          // 2 * HWD
#define KPAD   96             // padded K per half (3 MFMA K-steps of 32)

typedef __attribute__((ext_vector_type(8))) _Float16 f16x8;
typedef __attribute__((ext_vector_type(2))) __fp16   h16x2;   // cvt_pkrtz return type
typedef __attribute__((ext_vector_type(4))) float    f32x4;

union U2 { h16x2 h; unsigned u; };
union UF { unsigned u[4]; f16x8 v; };

// ---------------------------------------------------------------------------
// Table build: tbl[role][c][k], f16, k-major, zero-padded to KPAD.
//   role 0 = exp(k1), 1 = k1*exp(k1), 2 = exp(k2), 3 = k2*exp(k2)
// Zero padding at k>=75 is what makes clamped OOB x-loads harmless.
// ---------------------------------------------------------------------------
__global__ void smorph_build_tables(const float* __restrict__ k1,
                                    const float* __restrict__ k2,
                                    _Float16* __restrict__ tbl)
{
    int i = (int)blockIdx.x * 256 + (int)threadIdx.x;   // (dir, c, k)
    if (i >= 2 * 16 * KPAD) return;
    int dir = i / (16 * KPAD);
    int r   = i - dir * (16 * KPAD);
    int c   = r / KPAD;
    int k   = r - c * KPAD;
    const float* kw = dir ? k2 : k1;
    float a = 0.f, b = 0.f;
    if (k < PATCHD) {
        float w = kw[k * 16 + c];
        float e = __expf(w);
        a = e;
        b = w * e;
    }
    tbl[(dir * 2 + 0) * (16 * KPAD) + c * KPAD + k] = (_Float16)a;
    tbl[(dir * 2 + 1) * (16 * KPAD) + c * KPAD + k] = (_Float16)b;
}

// ---------------------------------------------------------------------------
// Main: straight-line, no LDS, no barriers. All 24 x-loads issued up front
// (clamped addresses for k>=75; zero table rows kill their contribution).
// Per K-step: 16 L1-hot table dwords, 16 exp, 16 pack-pairs, 6 MFMA.
// ---------------------------------------------------------------------------
__global__ __launch_bounds__(256, 4)
void smorph_mfma5(const float* __restrict__ x,
                  const _Float16* __restrict__ tbl,
                  const float* __restrict__ bias,
                  float* __restrict__ out)
{
    const int tid = (int)threadIdx.x;
    const int l   = tid & 63;
    const int w   = tid >> 6;
    const int g   = l >> 4;         // k-subgroup 0..3
    const int c   = l & 15;         // channel lane (A) / position lane (B,D)
    const int p0  = (int)blockIdx.x * 64 + w * 16;
    if (p0 >= NPOS) return;         // no barriers anywhere -> safe
    const int b   = (p0 >= HWD) ? 1 : 0;   // HWD % 16 == 0: no straddle
    const int hw0 = p0 - b * HWD;

    const float* xb = x + (size_t)b * PATCHD * HWD + hw0 + c;

    // ---- issue ALL x loads first: 3 steps x 8, addresses clamped to k=74 ----
    float xv[3][8];
    #pragma unroll
    for (int s = 0; s < 3; ++s)
        #pragma unroll
        for (int j = 0; j < 8; ++j) {
            int k = 32 * s + 8 * g + j;        // g is per-lane; s,j compile-time
            k = (k > PATCHD - 1) ? (PATCHD - 1) : k;   // only s==2 can clamp
            xv[s][j] = xb[(size_t)k * HWD];
        }

    const _Float16* t0 = tbl + c * KPAD;

    f32x4 aN1 = {0.f,0.f,0.f,0.f}, aD1 = {0.f,0.f,0.f,0.f};
    f32x4 aN2 = {0.f,0.f,0.f,0.f}, aD2 = {0.f,0.f,0.f,0.f};

    #pragma unroll
    for (int s = 0; s < 3; ++s) {
        // weight fragments for this step: 16 aligned dwords, L1-resident 12KB
        UF a1f, b1f, a2f, b2f;
        #pragma unroll
        for (int jp = 0; jp < 4; ++jp) {
            const int off = 32 * s + 8 * g + 2 * jp;
            a1f.u[jp] = *(const unsigned*)(t0 + 0 * 16 * KPAD + off);
            b1f.u[jp] = *(const unsigned*)(t0 + 1 * 16 * KPAD + off);
            a2f.u[jp] = *(const unsigned*)(t0 + 2 * 16 * KPAD + off);
            b2f.u[jp] = *(const unsigned*)(t0 + 3 * 16 * KPAD + off);
        }

        // features: E = exp(x), R = exp(-x) (independent, no rcp chain)
        float E[8], R[8];
        #pragma unroll
        for (int j = 0; j < 8; ++j) {
            E[j] = __expf(xv[s][j]);
            R[j] = __expf(-xv[s][j]);
        }

        UF fEx, fE, fRx, fR;
        #pragma unroll
        for (int jp = 0; jp < 4; ++jp) {
            const float x0 = xv[s][2*jp], x1 = xv[s][2*jp+1];
            U2 q;
            q.h = __builtin_amdgcn_cvt_pkrtz(E[2*jp] * x0,  E[2*jp+1] * x1);  fEx.u[jp] = q.u;
            q.h = __builtin_amdgcn_cvt_pkrtz(E[2*jp],       E[2*jp+1]);       fE.u[jp]  = q.u;
            q.h = __builtin_amdgcn_cvt_pkrtz(-R[2*jp] * x0, -R[2*jp+1] * x1); fRx.u[jp] = q.u;
            q.h = __builtin_amdgcn_cvt_pkrtz(R[2*jp],       R[2*jp+1]);       fR.u[jp]  = q.u;
        }

        aN1 = __builtin_amdgcn_mfma_f32_16x16x32_f16(a1f.v, fEx.v, aN1, 0, 0, 0);
        aN1 = __builtin_amdgcn_mfma_f32_16x16x32_f16(b1f.v, fE.v,  aN1, 0, 0, 0);
        aD1 = __builtin_amdgcn_mfma_f32_16x16x32_f16(a1f.v, fE.v,  aD1, 0, 0, 0);
        aN2 = __builtin_amdgcn_mfma_f32_16x16x32_f16(a2f.v, fRx.v, aN2, 0, 0, 0);
        aN2 = __builtin_amdgcn_mfma_f32_16x16x32_f16(b2f.v, fR.v,  aN2, 0, 0, 0);
        aD2 = __builtin_amdgcn_mfma_f32_16x16x32_f16(a2f.v, fR.v,  aD2, 0, 0, 0);
    }

    // ---- epilogue: y = num1/den1 + num2/den2 + bias; 64B-segment stores ----
    const float4 bsv = *(const float4*)(bias + 4 * g);
    float* ob = out + ((size_t)(b * 16 + 4 * g)) * HWD + hw0 + c;
    ob[0 * (size_t)HWD] = aN1[0] * __builtin_amdgcn_rcpf(aD1[0]) + aN2[0] * __builtin_amdgcn_rcpf(aD2[0]) + bsv.x;
    ob[1 * (size_t)HWD] = aN1[1] * __builtin_amdgcn_rcpf(aD1[1]) + aN2[1] * __builtin_amdgcn_rcpf(aD2[1]) + bsv.y;
    ob[2 * (size_t)HWD] = aN1[2] * __builtin_amdgcn_rcpf(aD1[2]) + aN2[2] * __builtin_amdgcn_rcpf(aD2[2]) + bsv.z;
    ob[3 * (size_t)HWD] = aN1[3] * __builtin_amdgcn_rcpf(aD1[3]) + aN2[3] * __builtin_amdgcn_rcpf(aD2[3]) + bsv.w;
}

extern "C" void kernel_launch(void* const* d_in, const int* in_sizes, int n_in,
                              void* d_out, int out_size, void* d_ws, size_t ws_size,
                              hipStream_t stream)
{
    const float* x    = (const float*)d_in[0];
    const float* k1   = (const float*)d_in[1];
    const float* k2   = (const float*)d_in[2];
    const float* bias = (const float*)d_in[3];
    float* out = (float*)d_out;
    _Float16* tbl = (_Float16*)d_ws;     // 12 KB

    smorph_build_tables<<<(2 * 16 * KPAD + 255) / 256, 256, 0, stream>>>(k1, k2, tbl);
    smorph_mfma5<<<(NPOS + 63) / 64, 256, 0, stream>>>(x, tbl, bias, out);
}